// Round 14
// baseline (353.186 us; speedup 1.0000x reference)
//
#include <hip/hip_runtime.h>

typedef __bf16 bf16;
typedef __bf16 b16x8 __attribute__((ext_vector_type(8)));
typedef __bf16 b16x4 __attribute__((ext_vector_type(4)));
typedef float f32x4 __attribute__((ext_vector_type(4)));

#define TB 256
#define LDA 136          // LDS tile row stride (bf16)
#define LDI 40           // indicator tile row stride (bf16)
#define NB 1024
#define NK 24
#define NE 552
#define NH 128
#define BEcnt (NB*NE)    // 565248
#define BNODE (NB*NK)    // 24576
#define EPS 1e-5f

// ---- stats region (floats) ----
#define S_BN1 0          // [8][256] bucketed sum/sumsq (k1)
#define S_BN3 2048       // [8][256] (k4a)
#define S_A2  4096       // [64][256] bucketed BN2 raw accum (k3 harvest atomics)
#define S_A4  20480      // [64][256] BN4
#define S_B41 36864      // [128] folded b41'
#define STATS_ZERO_BYTES 147456
// ---- bf16 weight cache (elements within WBF) ----
#define WB_M1W2 0
#define WB_M2W1 16384
#define WB_M2W2 49152
#define WB_M3W1 65536
#define WB_M3W2 81920
#define WB_M4W1 98304
#define WB_M4W2 147456
#define WB_M4W1S 163840   // runtime-folded: W41c * sc2[k]  (128x128)
// ---- byte offsets ----
#define OFF_WBF 150528ull
#define OFF_H1  516096ull
#define OFF_H3  (OFF_H1 + 6291456ull)
#define OFF_Y2R (OFF_H3 + 6291456ull)
#define OFF_Y2S (OFF_Y2R + 6291456ull)
#define OFF_Y4R (OFF_Y2S + 6291456ull)
#define OFF_Y4S (OFF_Y4R + 6291456ull)
#define OFF_Z2  (OFF_Y4S + 6291456ull)
#define OFF_Z4  (OFF_Z2  + 12582912ull)
#define OFF_H2  (OFF_Z4  + 12582912ull)   // bf16 h2: 144,703,488 B

__device__ __forceinline__ float elu(float x){ return x > 0.f ? x : __expf(x) - 1.f; }

// B-fragment from bf16 row-major W: lane l holds W[n0+(l&15)][k0+(l>>4)*8+j]
__device__ __forceinline__ void load_bfrags_bf(const bf16* W, int ldw, int k0,
                                               b16x8 bfr[4][2], int lane, int w){
  int n = lane & 15, q = lane >> 4;
  #pragma unroll
  for (int kb=0; kb<4; ++kb)
    #pragma unroll
    for (int t=0; t<2; ++t)
      bfr[kb][t] = *(const b16x8*)(W + (size_t)((w*2+t)*16 + n)*ldw + k0 + kb*32 + q*8);
}

template<int MT>
__device__ __forceinline__ void gemm_regB_t(const bf16* As, const b16x8 bfr[4][2],
                                            f32x4 acc[MT][2], int lane){
  int m = lane & 15, q = lane >> 4;
  #pragma unroll
  for (int kb=0; kb<4; ++kb){
    int ka = kb*32 + q*8;
    b16x8 a[MT];
    #pragma unroll
    for (int mt=0; mt<MT; ++mt)
      a[mt] = *(const b16x8*)(As + (mt*16+m)*LDA + ka);
    #pragma unroll
    for (int mt=0; mt<MT; ++mt)
      #pragma unroll
      for (int t=0; t<2; ++t)
        acc[mt][t] = __builtin_amdgcn_mfma_f32_16x16x32_bf16(a[mt], bfr[kb][t], acc[mt][t], 0,0,0);
  }
}

template<int MT>
__device__ __forceinline__ void zero_acc_t(f32x4 acc[MT][2]){
  #pragma unroll
  for (int mt=0; mt<MT; ++mt)
    #pragma unroll
    for (int t=0; t<2; ++t){ acc[mt][t][0]=0.f; acc[mt][t][1]=0.f; acc[mt][t][2]=0.f; acc[mt][t][3]=0.f; }
}

template<int MT>
__device__ __forceinline__ void epilogue_to_lds_t(const f32x4 acc[MT][2], const float* bias, bf16* As,
                                                  int lane, int w, int validRows){
  int q = lane >> 4, n = lane & 15;
  #pragma unroll
  for (int mt=0; mt<MT; ++mt)
    #pragma unroll
    for (int t=0; t<2; ++t){
      int col = (w*2+t)*16 + n;
      float bc = bias[col];
      #pragma unroll
      for (int i=0; i<4; ++i){
        int row = mt*16 + q*4 + i;
        float v = (row < validRows) ? elu(acc[mt][t][i] + bc) : 0.f;
        As[row*LDA + col] = (bf16)v;
      }
    }
}

template<int MT>
__device__ __forceinline__ void write_acc_bf_t(const f32x4 acc[MT][2], bf16* out, int lane, int w){
  int q = lane >> 4, n = lane & 15;
  #pragma unroll
  for (int mt=0; mt<MT; ++mt)
    #pragma unroll
    for (int t=0; t<2; ++t){
      int col = (w*2+t)*16 + n;
      #pragma unroll
      for (int i=0; i<4; ++i)
        out[(size_t)(mt*16 + q*4 + i)*NH + col] = (bf16)acc[mt][t][i];
    }
}

// 32-row tile store + bucketed stats (node kernels)
__device__ __forceinline__ void store_and_stats32(const bf16* As, bf16* g_out, float* bucket,
                                                  int tid){
  for (int i = tid; i < 32*16; i += TB){
    int row = i >> 4, c8 = (i & 15) << 3;
    *(b16x8*)(g_out + (size_t)row*NH + c8) = *(const b16x8*)(As + row*LDA + c8);
  }
  int c = tid & 127, half = tid >> 7;
  float s = 0.f, s2 = 0.f;
  for (int row = half; row < 32; row += 2){
    float v = (float)As[row*LDA + c];
    s += v; s2 += v*v;
  }
  atomicAdd(&bucket[c], s);
  atomicAdd(&bucket[128+c], s2);
}

// Register harvest core (edge kernels, MT=6): ELU(acc+bias), per-column stats + 4 recv-group
// sums in registers, shfl_down(32/16) tree; lane<16 stages z into LDS and atomicAdds the 4
// reduced stats values into the 64-bucket global accumulator.
// If As != nullptr the ELU'd values are also written to As (k3 materializes h2).
__device__ __forceinline__ void harvest_core(const f32x4 acc[6][2], const float* bias, bf16* As,
                                             float* zL, float* sacc, int lane, int w){
  int q4 = (lane >> 4) << 2, n = lane & 15;
  int c0 = w*32 + n, c1 = c0 + 16;
  float b0 = bias[c0], b1 = bias[c1];
  float zs0[4] = {0,0,0,0}, zs1[4] = {0,0,0,0};
  float s0=0.f, p0=0.f, s1=0.f, p1=0.f;
  #pragma unroll
  for (int mt=0; mt<6; ++mt){
    #pragma unroll
    for (int i=0; i<4; ++i){
      const int R0 = mt*16 + i;
      int row = R0 + q4;
      bool ok = row < 92;
      float v0 = elu(acc[mt][0][i] + b0); v0 = ok ? v0 : 0.f;
      float v1 = elu(acc[mt][1][i] + b1); v1 = ok ? v1 : 0.f;
      if (As){
        As[row*LDA + c0] = (bf16)v0;
        As[row*LDA + c1] = (bf16)v1;
      }
      s0 += v0; p0 += v0*v0; s1 += v1; p1 += v1*v1;
      const int gLo = (R0>=23)+(R0>=46)+(R0>=69);
      const int gHi = ((R0+12)>=23)+((R0+12)>=46)+((R0+12)>=69);
      if (gLo == gHi){
        zs0[gLo] += v0; zs1[gLo] += v1;
      } else {
        const int bnd = (gHi==1) ? 23 : ((gHi==2) ? 46 : 69);
        bool hi = row >= bnd;
        zs0[gLo] += hi ? 0.f : v0;  zs0[gHi] += hi ? v0 : 0.f;
        zs1[gLo] += hi ? 0.f : v1;  zs1[gHi] += hi ? v1 : 0.f;
      }
    }
  }
  #pragma unroll
  for (int g=0; g<4; ++g){
    zs0[g] += __shfl_down(zs0[g],32); zs0[g] += __shfl_down(zs0[g],16);
    zs1[g] += __shfl_down(zs1[g],32); zs1[g] += __shfl_down(zs1[g],16);
  }
  s0 += __shfl_down(s0,32); s0 += __shfl_down(s0,16);
  p0 += __shfl_down(p0,32); p0 += __shfl_down(p0,16);
  s1 += __shfl_down(s1,32); s1 += __shfl_down(s1,16);
  p1 += __shfl_down(p1,32); p1 += __shfl_down(p1,16);
  if (lane < 16){
    #pragma unroll
    for (int g=0; g<4; ++g){
      zL[g*NH + c0] = zs0[g];
      zL[g*NH + c1] = zs1[g];
    }
    atomicAdd(&sacc[c0], s0);     atomicAdd(&sacc[128+c0], p0);
    atomicAdd(&sacc[c1], s1);     atomicAdd(&sacc[128+c1], p1);
  }
}

// ---- K0: one-time fp32 -> bf16 weight conversion into ws ----
__global__ __launch_bounds__(TB) void k0_cvt(const float* __restrict__ s0, const float* __restrict__ s1,
    const float* __restrict__ s2, const float* __restrict__ s3, const float* __restrict__ s4,
    const float* __restrict__ s5, const float* __restrict__ s6, bf16* __restrict__ dst){
  int idx = (blockIdx.x*TB + threadIdx.x)*4;
  const float* sp; int base;
  if      (idx < 16384){ sp=s0; base=0; }
  else if (idx < 49152){ sp=s1; base=16384; }
  else if (idx < 65536){ sp=s2; base=49152; }
  else if (idx < 81920){ sp=s3; base=65536; }
  else if (idx < 98304){ sp=s4; base=81920; }
  else if (idx <147456){ sp=s5; base=98304; }
  else                 { sp=s6; base=147456; }
  f32x4 v = *(const f32x4*)(sp + (idx - base));
  b16x4 o; o[0]=(bf16)v[0]; o[1]=(bf16)v[1]; o[2]=(bf16)v[2]; o[3]=(bf16)v[3];
  *(b16x4*)(dst + idx) = o;
}

// ---- K_fold41: inline BN2 affine from 64-bucket accum, fold into skip weight ----
__global__ __launch_bounds__(TB) void k_fold41(const float* __restrict__ w41, const float* __restrict__ b41,
    const float* __restrict__ A2, const float* __restrict__ g2, const float* __restrict__ be2,
    bf16* __restrict__ w41s, float* __restrict__ b41f){
  __shared__ float tmp[256], scl[128], shf[128];
  int tid = threadIdx.x;
  { int c = tid & 127, part = tid >> 7;
    float s = 0.f;
    for (int r=0; r<64; ++r) s += A2[r*256 + part*128 + c];
    tmp[tid] = s; }
  __syncthreads();
  if (tid < 128){
    float mean = tmp[tid] / (float)BEcnt;
    float var  = tmp[128+tid] / (float)BEcnt - mean*mean;
    float sc = g2[tid] * rsqrtf(var + EPS);
    scl[tid] = sc; shf[tid] = be2[tid] - mean*sc;
  }
  __syncthreads();
  if (blockIdx.x < 16){
    int idx = (blockIdx.x*TB + tid)*4;        // [0, 16384)
    int o = idx >> 7, k = idx & 127;
    f32x4 v = *(const f32x4*)(w41 + (size_t)o*384 + 256 + k);
    b16x4 r;
    #pragma unroll
    for (int j=0; j<4; ++j) r[j] = (bf16)(v[j] * scl[k+j]);
    *(b16x4*)(w41s + idx) = r;
  } else if (tid < 128){
    const float* wr = w41 + (size_t)tid*384 + 256;
    float s = 0.f;
    for (int k=0; k<128; ++k) s += wr[k] * shf[k];
    b41f[tid] = b41[tid] + s;
  }
}

// ---- K1: MLP1 (6->128 VALU, 128->128 MFMA), 32-row tiles (768 blocks) ----
__global__ __launch_bounds__(TB) void k1_mlp1(const float* __restrict__ in,
    const float* __restrict__ w1, const float* __restrict__ b1,
    const bf16* __restrict__ w2, const float* __restrict__ b2,
    bf16* __restrict__ h1, float* __restrict__ bn1){
  __shared__ alignas(16) bf16 As[32*LDA];
  __shared__ float w1s[128*6];
  __shared__ float b1s[128], b2s[128];
  __shared__ float ins[32*6];
  int tid = threadIdx.x;
  int row0 = blockIdx.x * 32;
  for (int i=tid; i<768; i+=TB) w1s[i] = w1[i];
  if (tid < 128){ b1s[tid]=b1[tid]; b2s[tid]=b2[tid]; }
  for (int i=tid; i<192; i+=TB) ins[i] = in[row0*6 + i];
  __syncthreads();
  for (int i=tid; i<32*32; i+=TB){
    int row = i >> 5, c4 = (i & 31) << 2;
    float x0=ins[row*6+0], x1=ins[row*6+1], x2=ins[row*6+2],
          x3=ins[row*6+3], x4=ins[row*6+4], x5=ins[row*6+5];
    #pragma unroll
    for (int j=0; j<4; ++j){
      int c = c4 + j;
      const float* wr = w1s + c*6;
      float s = b1s[c] + wr[0]*x0 + wr[1]*x1 + wr[2]*x2 + wr[3]*x3 + wr[4]*x4 + wr[5]*x5;
      As[row*LDA + c] = (bf16)elu(s);
    }
  }
  int lane = tid & 63, w = tid >> 6;
  b16x8 bfr[4][2];
  load_bfrags_bf(w2, 128, 0, bfr, lane, w);
  __syncthreads();
  f32x4 acc[2][2]; zero_acc_t<2>(acc);
  gemm_regB_t<2>(As, bfr, acc, lane);
  __syncthreads();
  epilogue_to_lds_t<2>(acc, b2s, As, lane, w, 32);
  __syncthreads();
  store_and_stats32(As, h1 + (size_t)row0*NH, bn1 + (blockIdx.x & 7)*256, tid);
}

// ---- K2/K4b: fold BN affine (from 8-bucket stats), project yr/ys -> bf16; 32-row tiles ----
__global__ __launch_bounds__(TB) void k_project(const bf16* __restrict__ hin,
    const float* __restrict__ stats,
    const float* __restrict__ g, const float* __restrict__ be,
    const bf16* __restrict__ Wp, int ldw,
    bf16* __restrict__ yr, bf16* __restrict__ ys){
  __shared__ alignas(16) bf16 As[32*LDA];
  __shared__ float scl[128], shf[128];
  int tid = threadIdx.x;
  int row0 = blockIdx.x * 32;
  if (tid < 128){
    float s = 0.f, q2 = 0.f;
    #pragma unroll
    for (int k=0; k<8; ++k){ s += stats[k*256+tid]; q2 += stats[k*256+128+tid]; }
    float mean = s / (float)BNODE;
    float var  = q2 / (float)BNODE - mean*mean;
    float rs = rsqrtf(var + EPS);
    float sc = g[tid] * rs;
    scl[tid] = sc; shf[tid] = be[tid] - mean*sc;
  }
  __syncthreads();
  for (int i=tid; i<32*16; i+=TB){
    int row = i >> 4, c8 = (i & 15) << 3;
    b16x8 v = *(const b16x8*)(hin + (size_t)(row0+row)*NH + c8);
    b16x8 o;
    #pragma unroll
    for (int j=0; j<8; ++j) o[j] = (bf16)(scl[c8+j]*(float)v[j] + shf[c8+j]);
    *(b16x8*)(As + row*LDA + c8) = o;
  }
  int lane = tid & 63, w = tid >> 6;
  b16x8 bfr[4][2];
  load_bfrags_bf(Wp, ldw, 0, bfr, lane, w);
  __syncthreads();
  f32x4 acc[2][2]; zero_acc_t<2>(acc);
  gemm_regB_t<2>(As, bfr, acc, lane);
  write_acc_bf_t<2>(acc, yr + (size_t)row0*NH, lane, w);
  load_bfrags_bf(Wp, ldw, 128, bfr, lane, w);
  zero_acc_t<2>(acc);
  gemm_regB_t<2>(As, bfr, acc, lane);
  write_acc_bf_t<2>(acc, ys + (size_t)row0*NH, lane, w);
}

// ---- K3: PERSISTENT per-batch MLP2: 1024 blocks, 6 tiles each. y2s table + weight frags
//      staged once per block; per tile: build A, GEMM, harvest (h2 into As), write z2/h2 ----
__global__ __launch_bounds__(TB,4) void k3_edge1(const bf16* __restrict__ y2r, const bf16* __restrict__ y2s,
    const float* __restrict__ b21, const bf16* __restrict__ w22, const float* __restrict__ b22,
    float* __restrict__ z2, float* __restrict__ acc2, bf16* __restrict__ h2){
  __shared__ alignas(16) bf16 As[96*LDA];
  __shared__ alignas(16) bf16 yts[24*LDA];
  __shared__ float b1s[NH], b2s[NH];
  __shared__ float zL[512];
  int tid = threadIdx.x;
  int x = blockIdx.x & 7, bt = blockIdx.x >> 3;
  int b = x*128 + bt;                 // XCD-coherent batch mapping
  if (tid < NH){ b1s[tid]=b21[tid]; b2s[tid]=b22[tid]; }
  {  // stage y2s table once
    const bf16* ysB = y2s + (size_t)b*NK*NH;
    for (int i=tid; i<24*16; i+=TB){
      int r = i >> 4, c8 = (i & 15) << 3;
      *(b16x8*)(yts + r*LDA + c8) = *(const b16x8*)(ysB + (size_t)r*NH + c8);
    }
  }
  int lane = tid & 63, w = tid >> 6;
  b16x8 bfr[4][2];
  load_bfrags_bf(w22, 128, 0, bfr, lane, w);
  __syncthreads();
  for (int tile=0; tile<6; ++tile){
    int tile4 = tile*4;
    const bf16* yrG = y2r + ((size_t)b*NK + tile4)*NH;
    for (int i=tid; i<96*16; i+=TB){
      int row = i >> 4, c8 = (i & 15) << 3;
      b16x8 o;
      if (row < 92){
        int rl = (row>=23)+(row>=46)+(row>=69);
        int j = row - rl*23;
        int s = j + (j >= tile4 + rl);
        b16x8 vr = *(const b16x8*)(yrG + (size_t)rl*NH + c8);
        b16x8 vs = *(const b16x8*)(yts + s*LDA + c8);
        #pragma unroll
        for (int k=0; k<8; ++k) o[k] = (bf16)elu((float)vr[k] + (float)vs[k] + b1s[c8+k]);
      } else {
        #pragma unroll
        for (int k=0; k<8; ++k) o[k] = (bf16)0.f;
      }
      *(b16x8*)(As + row*LDA + c8) = o;
    }
    __syncthreads();
    f32x4 acc[6][2]; zero_acc_t<6>(acc);
    gemm_regB_t<6>(As, bfr, acc, lane);
    __syncthreads();                                // all waves done reading As(A2)
    harvest_core(acc, b2s, As, zL, acc2 + (blockIdx.x & 63)*256, lane, w);
    __syncthreads();                                // As(h2) + zL complete
    float* zdst = z2 + (size_t)(b*NK + tile4)*NH;
    if (tid < 128) ((f32x4*)zdst)[tid] = ((const f32x4*)zL)[tid];
    bf16* h2g = h2 + ((size_t)b*NE + tile4*23)*NH;
    for (int i=tid; i<92*16; i+=TB){
      int row = i >> 4, c8 = (i & 15) << 3;
      *(b16x8*)(h2g + (size_t)row*NH + c8) = *(const b16x8*)(As + row*LDA + c8);
    }
    __syncthreads();                                // h2 store done before As overwrite
  }
}

// ---- K4a: inline BN2 affine from 64-bucket accum; MLP3 on normalized edge2node(z2) ----
__global__ __launch_bounds__(TB) void k4a_mlp3(const float* __restrict__ z2,
    const float* __restrict__ A2,
    const float* __restrict__ g2, const float* __restrict__ be2,
    const bf16* __restrict__ w31, const float* __restrict__ b31,
    const bf16* __restrict__ w32, const float* __restrict__ b32,
    bf16* __restrict__ h3, float* __restrict__ bn3){
  __shared__ alignas(16) bf16 As[32*LDA];
  __shared__ float scl[128], shf[128], b1s[128], b2s[128];
  __shared__ float tmp[256];
  int tid = threadIdx.x;
  int row0 = blockIdx.x * 32;
  { int c = tid & 127, part = tid >> 7;
    float s = 0.f;
    for (int r=0; r<64; ++r) s += A2[r*256 + part*128 + c];
    tmp[tid] = s; }
  if (tid < 128){ b1s[tid] = b31[tid]; b2s[tid] = b32[tid]; }
  __syncthreads();
  if (tid < 128){
    float mean = tmp[tid] / (float)BEcnt;
    float var  = tmp[128+tid] / (float)BEcnt - mean*mean;
    float sc = g2[tid] * rsqrtf(var + EPS);
    scl[tid] = sc * (1.f/24.f);
    shf[tid] = (be2[tid] - mean*sc) * (23.f/24.f);
  }
  __syncthreads();
  for (int i=tid; i<32*32; i+=TB){
    int rl = i >> 5, c4 = (i & 31) << 2;
    f32x4 v = *(const f32x4*)(z2 + (size_t)(row0+rl)*NH + c4);
    b16x4 o;
    #pragma unroll
    for (int k=0; k<4; ++k) o[k] = (bf16)(scl[c4+k]*v[k] + shf[c4+k]);
    *(b16x4*)(As + rl*LDA + c4) = o;
  }
  int lane = tid & 63, w = tid >> 6;
  b16x8 bfr[4][2];
  load_bfrags_bf(w31, 128, 0, bfr, lane, w);
  __syncthreads();
  f32x4 acc[2][2]; zero_acc_t<2>(acc);
  gemm_regB_t<2>(As, bfr, acc, lane);
  __syncthreads();
  epilogue_to_lds_t<2>(acc, b1s, As, lane, w, 32);
  load_bfrags_bf(w32, 128, 0, bfr, lane, w);
  __syncthreads();
  zero_acc_t<2>(acc);
  gemm_regB_t<2>(As, bfr, acc, lane);
  __syncthreads();
  epilogue_to_lds_t<2>(acc, b2s, As, lane, w, 32);
  __syncthreads();
  store_and_stats32(As, h3 + (size_t)row0*NH, bn3 + (blockIdx.x & 7)*256, tid);
}

// ---- K5: PERSISTENT per-batch MLP4: 1024 blocks, 6 tiles each, augmented skip-GEMM.
//      w41s frags + y4s/bias part of the aug B-fragment staged once per block. ----
__global__ __launch_bounds__(TB,3) void k5_edge2(
    const bf16* __restrict__ h2,
    const bf16* __restrict__ y4r, const bf16* __restrict__ y4s,
    const bf16* __restrict__ w41s, const float* __restrict__ b41f,
    const bf16* __restrict__ w42, const float* __restrict__ b42,
    float* __restrict__ z4, float* __restrict__ acc4){
  __shared__ alignas(16) bf16 As[96*LDA];
  __shared__ alignas(16) bf16 Ai[96*LDI];     // indicator tile: 32 aug-K columns
  __shared__ float b42s[NH];
  __shared__ float zL[512];
  int tid = threadIdx.x;
  int x = blockIdx.x & 7, bt = blockIdx.x >> 3;
  int b = x*128 + bt;
  if (tid < NH) b42s[tid] = b42[tid];
  int lane = tid & 63, w = tid >> 6;
  b16x8 bfr1[4][2];
  load_bfrags_bf(w41s, 128, 0, bfr1, lane, w);      // folded skip weight (held for all tiles)
  // aug B-fragment persistent part: k in 4..27 -> y4s[k-4][o]; k==28 -> b41'[o]; k>28 -> 0
  b16x8 baug[2];
  const bf16* y4sG = y4s + (size_t)b*NK*NH;
  {
    int q = lane >> 4, n = lane & 15;
    #pragma unroll
    for (int t=0; t<2; ++t){
      int o = w*32 + t*16 + n;
      #pragma unroll
      for (int j=0; j<8; ++j){
        int k = q*8 + j;
        bf16 v;
        if (k >= 4 && k < 28)  v = y4sG[(size_t)(k-4)*NH + o];
        else if (k == 28)      v = (bf16)b41f[o];
        else                   v = (bf16)0.f;   // k<4 filled per tile
        baug[t][j] = v;
      }
    }
  }
  for (int tile=0; tile<6; ++tile){
    int tile4 = tile*4;
    // per-tile aug: k<4 -> y4r[tile4+k][o] (only q==0 lanes hold k<4)
    {
      const bf16* y4rG = y4r + ((size_t)b*NK + tile4)*NH;
      int q = lane >> 4, n = lane & 15;
      if (q == 0){
        #pragma unroll
        for (int t=0; t<2; ++t){
          int o = w*32 + t*16 + n;
          #pragma unroll
          for (int j=0; j<4; ++j)
            baug[t][j] = y4rG[(size_t)j*NH + o];
        }
      }
    }
    // indicator tile for this tile4
    for (int i=tid; i<96*4; i+=TB){
      int row = i >> 2, cb = (i & 3) << 3;
      int rl = (row>=23)+(row>=46)+(row>=69);
      int jj = row - rl*23;
      int s = jj + (jj >= tile4 + rl);
      b16x8 o;
      #pragma unroll
      for (int k2=0; k2<8; ++k2){
        int k = cb + k2;
        bool one = (row < 92) && (k == rl || k == 4+s || k == 28);
        o[k2] = one ? (bf16)1.f : (bf16)0.f;
      }
      *(b16x8*)(Ai + row*LDI + cb) = o;
    }
    // raw h2 tile copy -> As
    {
      const bf16* h2g = h2 + ((size_t)b*NE + tile4*23)*NH;
      for (int i=tid; i<96*16; i+=TB){
        int row = i >> 4, c8 = (i & 15) << 3;
        b16x8 o;
        if (row < 92){
          o = *(const b16x8*)(h2g + (size_t)row*NH + c8);
        } else {
          #pragma unroll
          for (int j=0; j<8; ++j) o[j] = (bf16)0.f;
        }
        *(b16x8*)(As + row*LDA + c8) = o;
      }
    }
    __syncthreads();                                // As(h2) + Ai ready
    f32x4 acc[6][2]; zero_acc_t<6>(acc);
    gemm_regB_t<6>(As, bfr1, acc, lane);            // skip part
    {  // augmented K-block
      int m = lane & 15, q = lane >> 4;
      #pragma unroll
      for (int mt=0; mt<6; ++mt){
        b16x8 a = *(const b16x8*)(Ai + (mt*16+m)*LDI + q*8);
        #pragma unroll
        for (int t=0; t<2; ++t)
          acc[mt][t] = __builtin_amdgcn_mfma_f32_16x16x32_bf16(a, baug[t], acc[mt][t], 0,0,0);
      }
    }
    b16x8 bfr2[4][2];
    load_bfrags_bf(w42, 128, 0, bfr2, lane, w);     // L2-hot per tile
    __syncthreads();                                // done reading As(h2)
    // A4 = ELU(acc) -> As (pad rows acc==0 -> 0)
    {
      int q = lane >> 4, n = lane & 15;
      #pragma unroll
      for (int mt=0; mt<6; ++mt)
        #pragma unroll
        for (int t=0; t<2; ++t){
          int col = w*32 + t*16 + n;
          #pragma unroll
          for (int i=0; i<4; ++i)
            As[(mt*16 + q*4 + i)*LDA + col] = (bf16)elu(acc[mt][t][i]);
        }
    }
    zero_acc_t<6>(acc);
    __syncthreads();                                // As(A4) ready
    gemm_regB_t<6>(As, bfr2, acc, lane);            // h4 pre-act = W42 @ A4
    harvest_core(acc, b42s, nullptr, zL, acc4 + (blockIdx.x & 63)*256, lane, w);
    __syncthreads();
    float* zdst = z4 + (size_t)(b*NK + tile4)*NH;
    if (tid < 128) ((f32x4*)zdst)[tid] = ((const f32x4*)zL)[tid];
    __syncthreads();                                // zL read done before next harvest
  }
}

// ---- K6: inline BN4 affine from 64-bucket accum; final 3072->2 projection ----
__global__ __launch_bounds__(TB) void k6_out(const float* __restrict__ z4,
    const float* __restrict__ A4,
    const float* __restrict__ g4, const float* __restrict__ be4,
    const float* __restrict__ fo_w, const float* __restrict__ fo_b, float* __restrict__ out){
  __shared__ float red[512];
  __shared__ float scl[128], shf[128];
  int tid = threadIdx.x, b = blockIdx.x;
  { int c = tid & 127, part = tid >> 7;
    float s = 0.f;
    for (int r=0; r<64; ++r) s += A4[r*256 + part*128 + c];
    red[tid] = s; }
  __syncthreads();
  if (tid < 128){
    float mean = red[tid] / (float)BEcnt;
    float var  = red[128+tid] / (float)BEcnt - mean*mean;
    float sc = g4[tid] * rsqrtf(var + EPS);
    scl[tid] = sc; shf[tid] = be4[tid] - mean*sc;
  }
  __syncthreads();
  const float inv24 = 1.f/24.f, f2324 = 23.f/24.f;
  float a0 = 0.f, a1 = 0.f;
  for (int i=tid; i<3072; i+=TB){
    int c = i & 127;
    float x = scl[c]*z4[(size_t)b*3072 + i]*inv24 + shf[c]*f2324;
    a0 += x * fo_w[i];
    a1 += x * fo_w[3072 + i];
  }
  __syncthreads();
  red[tid] = a0; red[256+tid] = a1;
  __syncthreads();
  for (int st=128; st>0; st>>=1){
    if (tid < st){ red[tid] += red[tid+st]; red[256+tid] += red[256+tid+st]; }
    __syncthreads();
  }
  if (tid == 0){
    out[b*2+0] = red[0] + fo_b[0];
    out[b*2+1] = red[256] + fo_b[1];
  }
}

extern "C" void kernel_launch(void* const* d_in, const int* in_sizes, int n_in,
                              void* d_out, int out_size, void* d_ws, size_t ws_size,
                              hipStream_t stream){
  (void)in_sizes; (void)n_in; (void)out_size; (void)ws_size;
  const float* inputs = (const float*)d_in[0];
  const float* fo_w  = (const float*)d_in[3];
  const float* fo_b  = (const float*)d_in[4];
  const float* m1_w1=(const float*)d_in[5];  const float* m1_b1=(const float*)d_in[6];
  const float* m1_w2=(const float*)d_in[7];  const float* m1_b2=(const float*)d_in[8];
  const float* m1_g =(const float*)d_in[9];  const float* m1_be=(const float*)d_in[10];
  const float* m2_w1=(const float*)d_in[11]; const float* m2_b1=(const float*)d_in[12];
  const float* m2_w2=(const float*)d_in[13]; const float* m2_b2=(const float*)d_in[14];
  const float* m2_g =(const float*)d_in[15]; const float* m2_be=(const float*)d_in[16];
  const float* m3_w1=(const float*)d_in[17]; const float* m3_b1=(const float*)d_in[18];
  const float* m3_w2=(const float*)d_in[19]; const float* m3_b2=(const float*)d_in[20];
  const float* m3_g =(const float*)d_in[21]; const float* m3_be=(const float*)d_in[22];
  const float* m4_w1=(const float*)d_in[23]; const float* m4_b1=(const float*)d_in[24];
  const float* m4_w2=(const float*)d_in[25]; const float* m4_b2=(const float*)d_in[26];
  const float* m4_g =(const float*)d_in[27]; const float* m4_be=(const float*)d_in[28];

  char* ws = (char*)d_ws;
  float* stats = (float*)ws;
  bf16* wbf = (bf16*)(ws + OFF_WBF);
  bf16* h1  = (bf16*)(ws + OFF_H1);
  bf16* h3  = (bf16*)(ws + OFF_H3);
  bf16* y2r = (bf16*)(ws + OFF_Y2R);
  bf16* y2s = (bf16*)(ws + OFF_Y2S);
  bf16* y4r = (bf16*)(ws + OFF_Y4R);
  bf16* y4s = (bf16*)(ws + OFF_Y4S);
  float* z2  = (float*)(ws + OFF_Z2);
  float* z4  = (float*)(ws + OFF_Z4);
  bf16* h2  = (bf16*)(ws + OFF_H2);
  float* out = (float*)d_out;

  (void)hipMemsetAsync(d_ws, 0, STATS_ZERO_BYTES, stream);   // all stat accumulators
  k0_cvt<<<160, TB, 0, stream>>>(m1_w2, m2_w1, m2_w2, m3_w1, m3_w2, m4_w1, m4_w2, wbf);
  k1_mlp1<<<768, TB, 0, stream>>>(inputs, m1_w1, m1_b1, wbf + WB_M1W2, m1_b2, h1, stats + S_BN1);
  k_project<<<768, TB, 0, stream>>>(h1, stats + S_BN1, m1_g, m1_be,
                                    wbf + WB_M2W1, 256, y2r, y2s);
  k3_edge1<<<1024, TB, 0, stream>>>(y2r, y2s, m2_b1, wbf + WB_M2W2, m2_b2, z2,
                                    stats + S_A2, h2);
  k_fold41<<<17, TB, 0, stream>>>(m4_w1, m4_b1, stats + S_A2, m2_g, m2_be,
                                  wbf + WB_M4W1S, stats + S_B41);
  k4a_mlp3<<<768, TB, 0, stream>>>(z2, stats + S_A2, m2_g, m2_be,
                                   wbf + WB_M3W1, m3_b1, wbf + WB_M3W2, m3_b2,
                                   h3, stats + S_BN3);
  k_project<<<768, TB, 0, stream>>>(h3, stats + S_BN3, m3_g, m3_be,
                                    wbf + WB_M4W1, 384, y4r, y4s);
  k5_edge2<<<1024, TB, 0, stream>>>(h2, y4r, y4s,
                                    wbf + WB_M4W1S, stats + S_B41,
                                    wbf + WB_M4W2, m4_b2, z4, stats + S_A4);
  k6_out<<<1024, TB, 0, stream>>>(z4, stats + S_A4, m4_g, m4_be, fo_w, fo_b, out);
}

// Round 15
// 320.698 us; speedup vs baseline: 1.1013x; 1.1013x over previous
//
#include <hip/hip_runtime.h>

typedef __bf16 bf16;
typedef __bf16 b16x8 __attribute__((ext_vector_type(8)));
typedef __bf16 b16x4 __attribute__((ext_vector_type(4)));
typedef float f32x4 __attribute__((ext_vector_type(4)));

#define TB 256
#define LDA 136          // LDS tile row stride (bf16)
#define LDI 40           // indicator tile row stride (bf16)
#define NB 1024
#define NK 24
#define NE 552
#define NH 128
#define BEcnt (NB*NE)    // 565248
#define BNODE (NB*NK)    // 24576
#define EPS 1e-5f

// ---- stats region (floats) ----
#define S_BN1 0          // [8][256] bucketed sum/sumsq (k1)
#define S_BN3 2048       // [8][256] (k4a)
#define S_A2  4096       // [32][256] bucketed BN2 raw accum (k3 harvest atomics)
#define S_A4  12288      // [32][256] BN4
#define S_B41 20480      // [128] folded b41'
#define STATS_ZERO_BYTES 81920
// ---- bf16 weight cache (elements within WBF) ----
#define WB_M1W2 0
#define WB_M2W1 16384
#define WB_M2W2 49152
#define WB_M3W1 65536
#define WB_M3W2 81920
#define WB_M4W1 98304
#define WB_M4W2 147456
#define WB_M4W1S 163840   // runtime-folded: W41c * sc2[k]  (128x128)
// ---- byte offsets ----
#define OFF_WBF 84992ull
#define OFF_H1  450560ull
#define OFF_H3  (OFF_H1 + 6291456ull)
#define OFF_Y2R (OFF_H3 + 6291456ull)
#define OFF_Y2S (OFF_Y2R + 6291456ull)
#define OFF_Y4R (OFF_Y2S + 6291456ull)
#define OFF_Y4S (OFF_Y4R + 6291456ull)
#define OFF_Z2  (OFF_Y4S + 6291456ull)
#define OFF_Z4  (OFF_Z2  + 12582912ull)
#define OFF_H2  (OFF_Z4  + 12582912ull)   // bf16 h2: 144,703,488 B

__device__ __forceinline__ float elu(float x){ return x > 0.f ? x : __expf(x) - 1.f; }

// XCD-coherent block swizzle: all 6 tiles of a batch land on the same XCD.
__device__ __forceinline__ void swizzle_bt(int id, int& b, int& tile4){
  int x = id & 7, j = id >> 3;
  int bt = j / 6;
  int tile = j - bt*6;
  b = x*128 + bt;
  tile4 = tile*4;
}

// B-fragment from bf16 row-major W: lane l holds W[n0+(l&15)][k0+(l>>4)*8+j]
__device__ __forceinline__ void load_bfrags_bf(const bf16* W, int ldw, int k0,
                                               b16x8 bfr[4][2], int lane, int w){
  int n = lane & 15, q = lane >> 4;
  #pragma unroll
  for (int kb=0; kb<4; ++kb)
    #pragma unroll
    for (int t=0; t<2; ++t)
      bfr[kb][t] = *(const b16x8*)(W + (size_t)((w*2+t)*16 + n)*ldw + k0 + kb*32 + q*8);
}

template<int MT>
__device__ __forceinline__ void gemm_regB_t(const bf16* As, const b16x8 bfr[4][2],
                                            f32x4 acc[MT][2], int lane){
  int m = lane & 15, q = lane >> 4;
  #pragma unroll
  for (int kb=0; kb<4; ++kb){
    int ka = kb*32 + q*8;
    b16x8 a[MT];
    #pragma unroll
    for (int mt=0; mt<MT; ++mt)
      a[mt] = *(const b16x8*)(As + (mt*16+m)*LDA + ka);
    #pragma unroll
    for (int mt=0; mt<MT; ++mt)
      #pragma unroll
      for (int t=0; t<2; ++t)
        acc[mt][t] = __builtin_amdgcn_mfma_f32_16x16x32_bf16(a[mt], bfr[kb][t], acc[mt][t], 0,0,0);
  }
}

template<int MT>
__device__ __forceinline__ void zero_acc_t(f32x4 acc[MT][2]){
  #pragma unroll
  for (int mt=0; mt<MT; ++mt)
    #pragma unroll
    for (int t=0; t<2; ++t){ acc[mt][t][0]=0.f; acc[mt][t][1]=0.f; acc[mt][t][2]=0.f; acc[mt][t][3]=0.f; }
}

template<int MT>
__device__ __forceinline__ void epilogue_to_lds_t(const f32x4 acc[MT][2], const float* bias, bf16* As,
                                                  int lane, int w, int validRows){
  int q = lane >> 4, n = lane & 15;
  #pragma unroll
  for (int mt=0; mt<MT; ++mt)
    #pragma unroll
    for (int t=0; t<2; ++t){
      int col = (w*2+t)*16 + n;
      float bc = bias[col];
      #pragma unroll
      for (int i=0; i<4; ++i){
        int row = mt*16 + q*4 + i;
        float v = (row < validRows) ? elu(acc[mt][t][i] + bc) : 0.f;
        As[row*LDA + col] = (bf16)v;
      }
    }
}

template<int MT>
__device__ __forceinline__ void write_acc_bf_t(const f32x4 acc[MT][2], bf16* out, int lane, int w){
  int q = lane >> 4, n = lane & 15;
  #pragma unroll
  for (int mt=0; mt<MT; ++mt)
    #pragma unroll
    for (int t=0; t<2; ++t){
      int col = (w*2+t)*16 + n;
      #pragma unroll
      for (int i=0; i<4; ++i)
        out[(size_t)(mt*16 + q*4 + i)*NH + col] = (bf16)acc[mt][t][i];
    }
}

// 32-row tile store + bucketed stats (node kernels)
__device__ __forceinline__ void store_and_stats32(const bf16* As, bf16* g_out, float* bucket,
                                                  int tid){
  for (int i = tid; i < 32*16; i += TB){
    int row = i >> 4, c8 = (i & 15) << 3;
    *(b16x8*)(g_out + (size_t)row*NH + c8) = *(const b16x8*)(As + row*LDA + c8);
  }
  int c = tid & 127, half = tid >> 7;
  float s = 0.f, s2 = 0.f;
  for (int row = half; row < 32; row += 2){
    float v = (float)As[row*LDA + c];
    s += v; s2 += v*v;
  }
  atomicAdd(&bucket[c], s);
  atomicAdd(&bucket[128+c], s2);
}

// Build A-tile from GLOBAL bf16 y-tables (XCD-L2-hot): rows = 4 recv groups x 23 edges; pad 92..95 = 0
__device__ __forceinline__ void build_A_g(bf16* As, const bf16* yrG, const bf16* ysG,
                                          const float* bias, int tile4, int tid){
  for (int i=tid; i<96*16; i+=TB){
    int row = i >> 4, c8 = (i & 15) << 3;
    b16x8 o;
    if (row < 92){
      int rl = (row>=23)+(row>=46)+(row>=69);
      int j = row - rl*23;
      int s = j + (j >= tile4 + rl);
      b16x8 vr = *(const b16x8*)(yrG + (size_t)rl*NH + c8);
      b16x8 vs = *(const b16x8*)(ysG + (size_t)s*NH + c8);
      #pragma unroll
      for (int k=0; k<8; ++k) o[k] = (bf16)elu((float)vr[k] + (float)vs[k] + bias[c8+k]);
    } else {
      #pragma unroll
      for (int k=0; k<8; ++k) o[k] = (bf16)0.f;
    }
    *(b16x8*)(As + row*LDA + c8) = o;
  }
}

// Register harvest core (edge kernels, MT=6): ELU(acc+bias), per-column stats + 4 recv-group
// sums in registers, shfl_down(32/16) tree; lane<16 stages z into LDS and atomicAdds the 4
// reduced stats values into the 32-bucket global accumulator.
// If As != nullptr the ELU'd values are also written to As (k3 materializes h2).
__device__ __forceinline__ void harvest_core(const f32x4 acc[6][2], const float* bias, bf16* As,
                                             float* zL, float* sacc, int lane, int w){
  int q4 = (lane >> 4) << 2, n = lane & 15;
  int c0 = w*32 + n, c1 = c0 + 16;
  float b0 = bias[c0], b1 = bias[c1];
  float zs0[4] = {0,0,0,0}, zs1[4] = {0,0,0,0};
  float s0=0.f, p0=0.f, s1=0.f, p1=0.f;
  #pragma unroll
  for (int mt=0; mt<6; ++mt){
    #pragma unroll
    for (int i=0; i<4; ++i){
      const int R0 = mt*16 + i;
      int row = R0 + q4;
      bool ok = row < 92;
      float v0 = elu(acc[mt][0][i] + b0); v0 = ok ? v0 : 0.f;
      float v1 = elu(acc[mt][1][i] + b1); v1 = ok ? v1 : 0.f;
      if (As){
        As[row*LDA + c0] = (bf16)v0;
        As[row*LDA + c1] = (bf16)v1;
      }
      s0 += v0; p0 += v0*v0; s1 += v1; p1 += v1*v1;
      const int gLo = (R0>=23)+(R0>=46)+(R0>=69);
      const int gHi = ((R0+12)>=23)+((R0+12)>=46)+((R0+12)>=69);
      if (gLo == gHi){
        zs0[gLo] += v0; zs1[gLo] += v1;
      } else {
        const int bnd = (gHi==1) ? 23 : ((gHi==2) ? 46 : 69);
        bool hi = row >= bnd;
        zs0[gLo] += hi ? 0.f : v0;  zs0[gHi] += hi ? v0 : 0.f;
        zs1[gLo] += hi ? 0.f : v1;  zs1[gHi] += hi ? v1 : 0.f;
      }
    }
  }
  #pragma unroll
  for (int g=0; g<4; ++g){
    zs0[g] += __shfl_down(zs0[g],32); zs0[g] += __shfl_down(zs0[g],16);
    zs1[g] += __shfl_down(zs1[g],32); zs1[g] += __shfl_down(zs1[g],16);
  }
  s0 += __shfl_down(s0,32); s0 += __shfl_down(s0,16);
  p0 += __shfl_down(p0,32); p0 += __shfl_down(p0,16);
  s1 += __shfl_down(s1,32); s1 += __shfl_down(s1,16);
  p1 += __shfl_down(p1,32); p1 += __shfl_down(p1,16);
  if (lane < 16){
    #pragma unroll
    for (int g=0; g<4; ++g){
      zL[g*NH + c0] = zs0[g];
      zL[g*NH + c1] = zs1[g];
    }
    atomicAdd(&sacc[c0], s0);     atomicAdd(&sacc[128+c0], p0);
    atomicAdd(&sacc[c1], s1);     atomicAdd(&sacc[128+c1], p1);
  }
}

// ---- K0: one-time fp32 -> bf16 weight conversion into ws ----
__global__ __launch_bounds__(TB) void k0_cvt(const float* __restrict__ s0, const float* __restrict__ s1,
    const float* __restrict__ s2, const float* __restrict__ s3, const float* __restrict__ s4,
    const float* __restrict__ s5, const float* __restrict__ s6, bf16* __restrict__ dst){
  int idx = (blockIdx.x*TB + threadIdx.x)*4;
  const float* sp; int base;
  if      (idx < 16384){ sp=s0; base=0; }
  else if (idx < 49152){ sp=s1; base=16384; }
  else if (idx < 65536){ sp=s2; base=49152; }
  else if (idx < 81920){ sp=s3; base=65536; }
  else if (idx < 98304){ sp=s4; base=81920; }
  else if (idx <147456){ sp=s5; base=98304; }
  else                 { sp=s6; base=147456; }
  f32x4 v = *(const f32x4*)(sp + (idx - base));
  b16x4 o; o[0]=(bf16)v[0]; o[1]=(bf16)v[1]; o[2]=(bf16)v[2]; o[3]=(bf16)v[3];
  *(b16x4*)(dst + idx) = o;
}

// ---- K_fold41: inline BN2 affine from 32-bucket accum, fold into skip weight ----
__global__ __launch_bounds__(TB) void k_fold41(const float* __restrict__ w41, const float* __restrict__ b41,
    const float* __restrict__ A2, const float* __restrict__ g2, const float* __restrict__ be2,
    bf16* __restrict__ w41s, float* __restrict__ b41f){
  __shared__ float tmp[256], scl[128], shf[128];
  int tid = threadIdx.x;
  { int c = tid & 127, part = tid >> 7;
    float s = 0.f;
    for (int r=0; r<32; ++r) s += A2[r*256 + part*128 + c];
    tmp[tid] = s; }
  __syncthreads();
  if (tid < 128){
    float mean = tmp[tid] / (float)BEcnt;
    float var  = tmp[128+tid] / (float)BEcnt - mean*mean;
    float sc = g2[tid] * rsqrtf(var + EPS);
    scl[tid] = sc; shf[tid] = be2[tid] - mean*sc;
  }
  __syncthreads();
  if (blockIdx.x < 16){
    int idx = (blockIdx.x*TB + tid)*4;        // [0, 16384)
    int o = idx >> 7, k = idx & 127;
    f32x4 v = *(const f32x4*)(w41 + (size_t)o*384 + 256 + k);
    b16x4 r;
    #pragma unroll
    for (int j=0; j<4; ++j) r[j] = (bf16)(v[j] * scl[k+j]);
    *(b16x4*)(w41s + idx) = r;
  } else if (tid < 128){
    const float* wr = w41 + (size_t)tid*384 + 256;
    float s = 0.f;
    for (int k=0; k<128; ++k) s += wr[k] * shf[k];
    b41f[tid] = b41[tid] + s;
  }
}

// ---- K1: MLP1 (6->128 VALU, 128->128 MFMA), 32-row tiles (768 blocks) ----
__global__ __launch_bounds__(TB) void k1_mlp1(const float* __restrict__ in,
    const float* __restrict__ w1, const float* __restrict__ b1,
    const bf16* __restrict__ w2, const float* __restrict__ b2,
    bf16* __restrict__ h1, float* __restrict__ bn1){
  __shared__ alignas(16) bf16 As[32*LDA];
  __shared__ float w1s[128*6];
  __shared__ float b1s[128], b2s[128];
  __shared__ float ins[32*6];
  int tid = threadIdx.x;
  int row0 = blockIdx.x * 32;
  for (int i=tid; i<768; i+=TB) w1s[i] = w1[i];
  if (tid < 128){ b1s[tid]=b1[tid]; b2s[tid]=b2[tid]; }
  for (int i=tid; i<192; i+=TB) ins[i] = in[row0*6 + i];
  __syncthreads();
  for (int i=tid; i<32*32; i+=TB){
    int row = i >> 5, c4 = (i & 31) << 2;
    float x0=ins[row*6+0], x1=ins[row*6+1], x2=ins[row*6+2],
          x3=ins[row*6+3], x4=ins[row*6+4], x5=ins[row*6+5];
    #pragma unroll
    for (int j=0; j<4; ++j){
      int c = c4 + j;
      const float* wr = w1s + c*6;
      float s = b1s[c] + wr[0]*x0 + wr[1]*x1 + wr[2]*x2 + wr[3]*x3 + wr[4]*x4 + wr[5]*x5;
      As[row*LDA + c] = (bf16)elu(s);
    }
  }
  int lane = tid & 63, w = tid >> 6;
  b16x8 bfr[4][2];
  load_bfrags_bf(w2, 128, 0, bfr, lane, w);
  __syncthreads();
  f32x4 acc[2][2]; zero_acc_t<2>(acc);
  gemm_regB_t<2>(As, bfr, acc, lane);
  __syncthreads();
  epilogue_to_lds_t<2>(acc, b2s, As, lane, w, 32);
  __syncthreads();
  store_and_stats32(As, h1 + (size_t)row0*NH, bn1 + (blockIdx.x & 7)*256, tid);
}

// ---- K2/K4b: fold BN affine (from 8-bucket stats), project yr/ys -> bf16; 32-row tiles ----
__global__ __launch_bounds__(TB) void k_project(const bf16* __restrict__ hin,
    const float* __restrict__ stats,
    const float* __restrict__ g, const float* __restrict__ be,
    const bf16* __restrict__ Wp, int ldw,
    bf16* __restrict__ yr, bf16* __restrict__ ys){
  __shared__ alignas(16) bf16 As[32*LDA];
  __shared__ float scl[128], shf[128];
  int tid = threadIdx.x;
  int row0 = blockIdx.x * 32;
  if (tid < 128){
    float s = 0.f, q2 = 0.f;
    #pragma unroll
    for (int k=0; k<8; ++k){ s += stats[k*256+tid]; q2 += stats[k*256+128+tid]; }
    float mean = s / (float)BNODE;
    float var  = q2 / (float)BNODE - mean*mean;
    float rs = rsqrtf(var + EPS);
    float sc = g[tid] * rs;
    scl[tid] = sc; shf[tid] = be[tid] - mean*sc;
  }
  __syncthreads();
  for (int i=tid; i<32*16; i+=TB){
    int row = i >> 4, c8 = (i & 15) << 3;
    b16x8 v = *(const b16x8*)(hin + (size_t)(row0+row)*NH + c8);
    b16x8 o;
    #pragma unroll
    for (int j=0; j<8; ++j) o[j] = (bf16)(scl[c8+j]*(float)v[j] + shf[c8+j]);
    *(b16x8*)(As + row*LDA + c8) = o;
  }
  int lane = tid & 63, w = tid >> 6;
  b16x8 bfr[4][2];
  load_bfrags_bf(Wp, ldw, 0, bfr, lane, w);
  __syncthreads();
  f32x4 acc[2][2]; zero_acc_t<2>(acc);
  gemm_regB_t<2>(As, bfr, acc, lane);
  write_acc_bf_t<2>(acc, yr + (size_t)row0*NH, lane, w);
  load_bfrags_bf(Wp, ldw, 128, bfr, lane, w);
  zero_acc_t<2>(acc);
  gemm_regB_t<2>(As, bfr, acc, lane);
  write_acc_bf_t<2>(acc, ys + (size_t)row0*NH, lane, w);
}

// ---- K3: per-edge MLP2 (launch_bounds (TB,4) — R11-verified; 6144 short blocks) ----
__global__ __launch_bounds__(TB,4) void k3_edge1(const bf16* __restrict__ y2r, const bf16* __restrict__ y2s,
    const float* __restrict__ b21, const bf16* __restrict__ w22, const float* __restrict__ b22,
    float* __restrict__ z2, float* __restrict__ acc2, bf16* __restrict__ h2){
  __shared__ alignas(16) bf16 As[96*LDA];
  __shared__ float b1s[NH], b2s[NH];
  __shared__ float zL[512];
  int tid = threadIdx.x;
  int b, tile4; swizzle_bt(blockIdx.x, b, tile4);
  if (tid < NH){ b1s[tid]=b21[tid]; b2s[tid]=b22[tid]; }
  int lane = tid & 63, w = tid >> 6;
  b16x8 bfr[4][2];
  load_bfrags_bf(w22, 128, 0, bfr, lane, w);
  __syncthreads();
  build_A_g(As, y2r + ((size_t)b*NK + tile4)*NH, y2s + (size_t)b*NK*NH, b1s, tile4, tid);
  __syncthreads();
  f32x4 acc[6][2]; zero_acc_t<6>(acc);
  gemm_regB_t<6>(As, bfr, acc, lane);
  __syncthreads();                                  // all waves done reading As(A2)
  harvest_core(acc, b2s, As, zL, acc2 + (blockIdx.x & 31)*256, lane, w);
  __syncthreads();                                  // As(h2) + zL complete
  float* zdst = z2 + (size_t)(b*NK + tile4)*NH;
  if (tid < 128) ((f32x4*)zdst)[tid] = ((const f32x4*)zL)[tid];
  bf16* h2g = h2 + ((size_t)b*NE + tile4*23)*NH;
  for (int i=tid; i<92*16; i+=TB){
    int row = i >> 4, c8 = (i & 15) << 3;
    *(b16x8*)(h2g + (size_t)row*NH + c8) = *(const b16x8*)(As + row*LDA + c8);
  }
}

// ---- K4a: inline BN2 affine from 32-bucket accum; MLP3 on normalized edge2node(z2) ----
__global__ __launch_bounds__(TB) void k4a_mlp3(const float* __restrict__ z2,
    const float* __restrict__ A2,
    const float* __restrict__ g2, const float* __restrict__ be2,
    const bf16* __restrict__ w31, const float* __restrict__ b31,
    const bf16* __restrict__ w32, const float* __restrict__ b32,
    bf16* __restrict__ h3, float* __restrict__ bn3){
  __shared__ alignas(16) bf16 As[32*LDA];
  __shared__ float scl[128], shf[128], b1s[128], b2s[128];
  __shared__ float tmp[256];
  int tid = threadIdx.x;
  int row0 = blockIdx.x * 32;
  { int c = tid & 127, part = tid >> 7;
    float s = 0.f;
    for (int r=0; r<32; ++r) s += A2[r*256 + part*128 + c];
    tmp[tid] = s; }
  if (tid < 128){ b1s[tid] = b31[tid]; b2s[tid] = b32[tid]; }
  __syncthreads();
  if (tid < 128){
    float mean = tmp[tid] / (float)BEcnt;
    float var  = tmp[128+tid] / (float)BEcnt - mean*mean;
    float sc = g2[tid] * rsqrtf(var + EPS);
    scl[tid] = sc * (1.f/24.f);
    shf[tid] = (be2[tid] - mean*sc) * (23.f/24.f);
  }
  __syncthreads();
  for (int i=tid; i<32*32; i+=TB){
    int rl = i >> 5, c4 = (i & 31) << 2;
    f32x4 v = *(const f32x4*)(z2 + (size_t)(row0+rl)*NH + c4);
    b16x4 o;
    #pragma unroll
    for (int k=0; k<4; ++k) o[k] = (bf16)(scl[c4+k]*v[k] + shf[c4+k]);
    *(b16x4*)(As + rl*LDA + c4) = o;
  }
  int lane = tid & 63, w = tid >> 6;
  b16x8 bfr[4][2];
  load_bfrags_bf(w31, 128, 0, bfr, lane, w);
  __syncthreads();
  f32x4 acc[2][2]; zero_acc_t<2>(acc);
  gemm_regB_t<2>(As, bfr, acc, lane);
  __syncthreads();
  epilogue_to_lds_t<2>(acc, b1s, As, lane, w, 32);
  load_bfrags_bf(w32, 128, 0, bfr, lane, w);
  __syncthreads();
  zero_acc_t<2>(acc);
  gemm_regB_t<2>(As, bfr, acc, lane);
  __syncthreads();
  epilogue_to_lds_t<2>(acc, b2s, As, lane, w, 32);
  __syncthreads();
  store_and_stats32(As, h3 + (size_t)row0*NH, bn3 + (blockIdx.x & 7)*256, tid);
}

// ---- K5: per-edge MLP4 with augmented skip-GEMM (R13 structure, 6144 short blocks) ----
__global__ __launch_bounds__(TB,3) void k5_edge2(
    const bf16* __restrict__ h2,
    const bf16* __restrict__ y4r, const bf16* __restrict__ y4s,
    const bf16* __restrict__ w41s, const float* __restrict__ b41f,
    const bf16* __restrict__ w42, const float* __restrict__ b42,
    float* __restrict__ z4, float* __restrict__ acc4){
  __shared__ alignas(16) bf16 As[96*LDA];
  __shared__ alignas(16) bf16 Ai[96*LDI];     // indicator tile: 32 aug-K columns
  __shared__ float b42s[NH];
  __shared__ float zL[512];
  int tid = threadIdx.x;
  int b, tile4; swizzle_bt(blockIdx.x, b, tile4);
  if (tid < NH) b42s[tid] = b42[tid];
  int lane = tid & 63, w = tid >> 6;
  b16x8 bfr[4][2];
  load_bfrags_bf(w41s, 128, 0, bfr, lane, w);       // folded skip weight
  // aug B-fragment: Waug[o][k] = y4r[k][o] (k<4) | y4s[k-4][o] (k<28) | b41'[o] (k==28) | 0
  b16x8 baug[2];
  {
    const bf16* y4rG = y4r + ((size_t)b*NK + tile4)*NH;
    const bf16* y4sG = y4s + (size_t)b*NK*NH;
    int q = lane >> 4, n = lane & 15;
    #pragma unroll
    for (int t=0; t<2; ++t){
      int o = w*32 + t*16 + n;
      #pragma unroll
      for (int j=0; j<8; ++j){
        int k = q*8 + j;
        bf16 v;
        if (k < 4)        v = y4rG[(size_t)k*NH + o];
        else if (k < 28)  v = y4sG[(size_t)(k-4)*NH + o];
        else if (k == 28) v = (bf16)b41f[o];
        else              v = (bf16)0.f;
        baug[t][j] = v;
      }
    }
  }
  // indicator tile: row<92 -> ones at k=rl(row), 4+s(row), 28; rows 92..95 all zero
  for (int i=tid; i<96*4; i+=TB){
    int row = i >> 2, cb = (i & 3) << 3;
    int rl = (row>=23)+(row>=46)+(row>=69);
    int jj = row - rl*23;
    int s = jj + (jj >= tile4 + rl);
    b16x8 o;
    #pragma unroll
    for (int k2=0; k2<8; ++k2){
      int k = cb + k2;
      bool one = (row < 92) && (k == rl || k == 4+s || k == 28);
      o[k2] = one ? (bf16)1.f : (bf16)0.f;
    }
    *(b16x8*)(Ai + row*LDI + cb) = o;
  }
  // raw h2 tile copy -> As (affine folded into w41s/b41f)
  {
    const bf16* h2g = h2 + ((size_t)b*NE + tile4*23)*NH;
    for (int i=tid; i<96*16; i+=TB){
      int row = i >> 4, c8 = (i & 15) << 3;
      b16x8 o;
      if (row < 92){
        o = *(const b16x8*)(h2g + (size_t)row*NH + c8);
      } else {
        #pragma unroll
        for (int j=0; j<8; ++j) o[j] = (bf16)0.f;
      }
      *(b16x8*)(As + row*LDA + c8) = o;
    }
  }
  __syncthreads();                                  // As(h2) + Ai ready
  f32x4 acc[6][2]; zero_acc_t<6>(acc);
  gemm_regB_t<6>(As, bfr, acc, lane);               // skip part
  // augmented K-block: A from indicator tile, B = y4 tables/bias
  {
    int m = lane & 15, q = lane >> 4;
    #pragma unroll
    for (int mt=0; mt<6; ++mt){
      b16x8 a = *(const b16x8*)(Ai + (mt*16+m)*LDI + q*8);
      #pragma unroll
      for (int t=0; t<2; ++t)
        acc[mt][t] = __builtin_amdgcn_mfma_f32_16x16x32_bf16(a, baug[t], acc[mt][t], 0,0,0);
    }
  }
  load_bfrags_bf(w42, 128, 0, bfr, lane, w);
  __syncthreads();                                  // done reading As(h2)
  // epilogue: A4 = ELU(acc) -> As (pad rows have acc==0 -> ELU=0)
  {
    int q = lane >> 4, n = lane & 15;
    #pragma unroll
    for (int mt=0; mt<6; ++mt)
      #pragma unroll
      for (int t=0; t<2; ++t){
        int col = w*32 + t*16 + n;
        #pragma unroll
        for (int i=0; i<4; ++i)
          As[(mt*16 + q*4 + i)*LDA + col] = (bf16)elu(acc[mt][t][i]);
      }
  }
  zero_acc_t<6>(acc);
  __syncthreads();                                  // As(A4) ready
  gemm_regB_t<6>(As, bfr, acc, lane);               // h4 pre-act = W42 @ A4
  harvest_core(acc, b42s, nullptr, zL, acc4 + (blockIdx.x & 31)*256, lane, w);
  __syncthreads();
  float* zdst = z4 + (size_t)(b*NK + tile4)*NH;
  if (tid < 128) ((f32x4*)zdst)[tid] = ((const f32x4*)zL)[tid];
}

// ---- K6: inline BN4 affine from 32-bucket accum; final 3072->2 projection ----
__global__ __launch_bounds__(TB) void k6_out(const float* __restrict__ z4,
    const float* __restrict__ A4,
    const float* __restrict__ g4, const float* __restrict__ be4,
    const float* __restrict__ fo_w, const float* __restrict__ fo_b, float* __restrict__ out){
  __shared__ float red[512];
  __shared__ float scl[128], shf[128];
  int tid = threadIdx.x, b = blockIdx.x;
  { int c = tid & 127, part = tid >> 7;
    float s = 0.f;
    for (int r=0; r<32; ++r) s += A4[r*256 + part*128 + c];
    red[tid] = s; }
  __syncthreads();
  if (tid < 128){
    float mean = red[tid] / (float)BEcnt;
    float var  = red[128+tid] / (float)BEcnt - mean*mean;
    float sc = g4[tid] * rsqrtf(var + EPS);
    scl[tid] = sc; shf[tid] = be4[tid] - mean*sc;
  }
  __syncthreads();
  const float inv24 = 1.f/24.f, f2324 = 23.f/24.f;
  float a0 = 0.f, a1 = 0.f;
  for (int i=tid; i<3072; i+=TB){
    int c = i & 127;
    float x = scl[c]*z4[(size_t)b*3072 + i]*inv24 + shf[c]*f2324;
    a0 += x * fo_w[i];
    a1 += x * fo_w[3072 + i];
  }
  __syncthreads();
  red[tid] = a0; red[256+tid] = a1;
  __syncthreads();
  for (int st=128; st>0; st>>=1){
    if (tid < st){ red[tid] += red[tid+st]; red[256+tid] += red[256+tid+st]; }
    __syncthreads();
  }
  if (tid == 0){
    out[b*2+0] = red[0] + fo_b[0];
    out[b*2+1] = red[256] + fo_b[1];
  }
}

extern "C" void kernel_launch(void* const* d_in, const int* in_sizes, int n_in,
                              void* d_out, int out_size, void* d_ws, size_t ws_size,
                              hipStream_t stream){
  (void)in_sizes; (void)n_in; (void)out_size; (void)ws_size;
  const float* inputs = (const float*)d_in[0];
  const float* fo_w  = (const float*)d_in[3];
  const float* fo_b  = (const float*)d_in[4];
  const float* m1_w1=(const float*)d_in[5];  const float* m1_b1=(const float*)d_in[6];
  const float* m1_w2=(const float*)d_in[7];  const float* m1_b2=(const float*)d_in[8];
  const float* m1_g =(const float*)d_in[9];  const float* m1_be=(const float*)d_in[10];
  const float* m2_w1=(const float*)d_in[11]; const float* m2_b1=(const float*)d_in[12];
  const float* m2_w2=(const float*)d_in[13]; const float* m2_b2=(const float*)d_in[14];
  const float* m2_g =(const float*)d_in[15]; const float* m2_be=(const float*)d_in[16];
  const float* m3_w1=(const float*)d_in[17]; const float* m3_b1=(const float*)d_in[18];
  const float* m3_w2=(const float*)d_in[19]; const float* m3_b2=(const float*)d_in[20];
  const float* m3_g =(const float*)d_in[21]; const float* m3_be=(const float*)d_in[22];
  const float* m4_w1=(const float*)d_in[23]; const float* m4_b1=(const float*)d_in[24];
  const float* m4_w2=(const float*)d_in[25]; const float* m4_b2=(const float*)d_in[26];
  const float* m4_g =(const float*)d_in[27]; const float* m4_be=(const float*)d_in[28];

  char* ws = (char*)d_ws;
  float* stats = (float*)ws;
  bf16* wbf = (bf16*)(ws + OFF_WBF);
  bf16* h1  = (bf16*)(ws + OFF_H1);
  bf16* h3  = (bf16*)(ws + OFF_H3);
  bf16* y2r = (bf16*)(ws + OFF_Y2R);
  bf16* y2s = (bf16*)(ws + OFF_Y2S);
  bf16* y4r = (bf16*)(ws + OFF_Y4R);
  bf16* y4s = (bf16*)(ws + OFF_Y4S);
  float* z2  = (float*)(ws + OFF_Z2);
  float* z4  = (float*)(ws + OFF_Z4);
  bf16* h2  = (bf16*)(ws + OFF_H2);
  float* out = (float*)d_out;

  (void)hipMemsetAsync(d_ws, 0, STATS_ZERO_BYTES, stream);   // all stat accumulators
  k0_cvt<<<160, TB, 0, stream>>>(m1_w2, m2_w1, m2_w2, m3_w1, m3_w2, m4_w1, m4_w2, wbf);
  k1_mlp1<<<768, TB, 0, stream>>>(inputs, m1_w1, m1_b1, wbf + WB_M1W2, m1_b2, h1, stats + S_BN1);
  k_project<<<768, TB, 0, stream>>>(h1, stats + S_BN1, m1_g, m1_be,
                                    wbf + WB_M2W1, 256, y2r, y2s);
  k3_edge1<<<6144, TB, 0, stream>>>(y2r, y2s, m2_b1, wbf + WB_M2W2, m2_b2, z2,
                                    stats + S_A2, h2);
  k_fold41<<<17, TB, 0, stream>>>(m4_w1, m4_b1, stats + S_A2, m2_g, m2_be,
                                  wbf + WB_M4W1S, stats + S_B41);
  k4a_mlp3<<<768, TB, 0, stream>>>(z2, stats + S_A2, m2_g, m2_be,
                                   wbf + WB_M3W1, m3_b1, wbf + WB_M3W2, m3_b2,
                                   h3, stats + S_BN3);
  k_project<<<768, TB, 0, stream>>>(h3, stats + S_BN3, m3_g, m3_be,
                                    wbf + WB_M4W1, 384, y4r, y4s);
  k5_edge2<<<6144, TB, 0, stream>>>(h2, y4r, y4s,
                                    wbf + WB_M4W1S, stats + S_B41,
                                    wbf + WB_M4W2, m4_b2, z4, stats + S_A4);
  k6_out<<<1024, TB, 0, stream>>>(z4, stats + S_A4, m4_g, m4_be, fo_w, fo_b, out);
}